// Round 1
// 150.978 us; speedup vs baseline: 1.0069x; 1.0069x over previous
//
#include <hip/hip_runtime.h>
#include <math.h>

// Problem: B=8, C=256, N=H*W=1024, nh=8, dk=dv=32. fp32 in/out, bf16 ws.
// Round 18: kill the fp32->bf16 VALU tax with v_cvt_pk_bf16_f32.
//   K1 qkv : 2 heads/block (halve x-tile restage), cvt_pk staging+epilogue,
//            q pre-scaled by 1/sqrt(dk)*log2(e); V written key-permuted.
//   K2 attn: exp2f softmax, P packed per-lane-contiguous (key-permuted
//            storage) -> 4 cvt_pk + 1 ds_write_b128 per row; middle barrier
//            dropped (plds traffic is intra-wave).
//   K3 oproj: unchanged structure; pack8 now 4 cvt_pk (was ~40 VALU).
typedef unsigned short u16;
typedef __attribute__((ext_vector_type(8))) unsigned short u16x8;
typedef __attribute__((ext_vector_type(8))) short s16x8;   // MFMA A/B frag
typedef __attribute__((ext_vector_type(4))) float f32x4;   // MFMA C/D

// logits scale 1/sqrt(32) folded with log2(e) so softmax uses exp2 directly
#define QK_SCALE (0.17677669529663687f * 1.4426950408889634f)

__device__ __forceinline__ unsigned cvt2(float lo, float hi) {
  unsigned r;  // D[15:0]=bf16_rne(lo), D[31:16]=bf16_rne(hi)
  asm("v_cvt_pk_bf16_f32 %0, %1, %2" : "=v"(r) : "v"(lo), "v"(hi));
  return r;
}
__device__ __forceinline__ u16 f2bf(float f) { return (u16)cvt2(f, f); }
__device__ __forceinline__ u16x8 ld16(const void* p) { u16x8 v; __builtin_memcpy(&v, p, 16); return v; }
__device__ __forceinline__ void st16(void* p, u16x8 v) { __builtin_memcpy(p, &v, 16); }
__device__ __forceinline__ void st16s(void* p, s16x8 v) { __builtin_memcpy(p, &v, 16); }
__device__ __forceinline__ void st4(void* p, unsigned v) { __builtin_memcpy(p, &v, 4); }
__device__ __forceinline__ f32x4 ldf4(const void* p) { f32x4 v; __builtin_memcpy(&v, p, 16); return v; }
__device__ __forceinline__ void stf4(void* p, f32x4 v) { __builtin_memcpy(p, &v, 16); }
__device__ __forceinline__ s16x8 frag16(const void* p) { s16x8 v; __builtin_memcpy(&v, p, 16); return v; }
__device__ __forceinline__ s16x8 pack8(f32x4 lo, f32x4 hi) {
  union { unsigned u[4]; s16x8 s; } c;
  c.u[0] = cvt2(lo.x, lo.y); c.u[1] = cvt2(lo.z, lo.w);
  c.u[2] = cvt2(hi.x, hi.y); c.u[3] = cvt2(hi.z, hi.w);
  return c.s;
}

// ---------------------------------------------------------------------------
// K1: QKV projection via MFMA. Grid (16 nt, 4 head-pairs, 8 b), 256 thr.
// Block: heads {2hp, 2hp+1}, 64-n tile. Wave w = ntile w (16 n). K=256, 8x32.
// LDS: xt[64][264] bf16 (x^T tile, [n][c]) 33.8KB + wlds[192][40] 15KB.
// wlds rows: [0,64)=Wq(h0,h1) [64,128)=Wk [128,192)=Wv; mt = m*4+hh*2+half.
// Epilogue: q,k -> [bh][n][d] (q pre-scaled, dword-pair stores);
//           v -> [bh][d][nperm], key-permuted within each 128-chunk:
//           nperm = (n&~127) | ((n%16)*8 + (n%128)/16  )  [c(sigma)]
// ---------------------------------------------------------------------------
__global__ __launch_bounds__(256) void r18_qkv(
    const float* __restrict__ x,
    const float* __restrict__ Wq, const float* __restrict__ bq,
    const float* __restrict__ Wk, const float* __restrict__ bk,
    const float* __restrict__ Wv, const float* __restrict__ bv,
    u16* __restrict__ qo, u16* __restrict__ ko, u16* __restrict__ vo)
{
  __shared__ u16 xt[64][264];    // [n_local][c], row stride 528B
  __shared__ u16 wlds[192][40];

  const int t = threadIdx.x;
  const int ntile = blockIdx.x, hp = blockIdx.y, b = blockIdx.z;
  const int n0 = ntile * 64, h0 = hp * 2;
  const int w = t >> 6, lane = t & 63, l15 = lane & 15, quad = lane >> 4;

  {  // stage x^T: thread t = channel c, 64 n (fp32 -> bf16, transposed)
    const float* xrow = x + ((size_t)b * 256 + t) * 1024 + n0;
#pragma unroll
    for (int i = 0; i < 64; i += 4) {
      const f32x4 a = ldf4(xrow + i);
      xt[i + 0][t] = f2bf(a.x); xt[i + 1][t] = f2bf(a.y);
      xt[i + 2][t] = f2bf(a.z); xt[i + 3][t] = f2bf(a.w);
    }
  }

  f32x4 acc[12];
#pragma unroll
  for (int i = 0; i < 12; ++i) acc[i] = (f32x4){0.f, 0.f, 0.f, 0.f};

  for (int ks = 0; ks < 8; ++ks) {
    __syncthreads();   // protect wlds reuse (and xt staging on ks=0)
    if (t < 192) {     // stage W chunk: thread t = one 32-c row
      const int m = t >> 6, hh = (t >> 5) & 1, r = t & 31;
      const float* M = (m == 0) ? Wq : (m == 1) ? Wk : Wv;
      const float* src = M + (size_t)((h0 + hh) * 32 + r) * 256 + ks * 32;
      st16s(&wlds[t][0],  pack8(ldf4(src),      ldf4(src + 4)));
      st16s(&wlds[t][8],  pack8(ldf4(src + 8),  ldf4(src + 12)));
      st16s(&wlds[t][16], pack8(ldf4(src + 16), ldf4(src + 20)));
      st16s(&wlds[t][24], pack8(ldf4(src + 24), ldf4(src + 28)));
    }
    __syncthreads();

    const s16x8 bfrag = frag16(&xt[w * 16 + l15][ks * 32 + quad * 8]);
#pragma unroll
    for (int mt = 0; mt < 12; ++mt) {
      const s16x8 af = frag16(&wlds[mt * 16 + l15][quad * 8]);
      acc[mt] = __builtin_amdgcn_mfma_f32_16x16x32_bf16(af, bfrag, acc[mt], 0, 0, 0);
    }
  }

  // epilogue: C/D row = quad*4+rr (d within 16), col = l15 (n within 16)
  const int n = n0 + w * 16 + l15;
  const int sig = n & 127;
  const int nperm = (n & ~127) | ((sig & 15) << 3) | (sig >> 4);
#pragma unroll
  for (int hh = 0; hh < 2; ++hh) {
    const int h = h0 + hh;
    const size_t bh = (size_t)(b * 8 + h);
    u16* qrow = qo + (bh * 1024 + n) * 32;
    u16* krow = ko + (bh * 1024 + n) * 32;
#pragma unroll
    for (int half = 0; half < 2; ++half) {
      const int d0 = half * 16 + quad * 4;
      const f32x4 aq = acc[hh * 2 + half];
      const f32x4 ak = acc[4 + hh * 2 + half];
      const f32x4 av = acc[8 + hh * 2 + half];
      st4(qrow + d0,     cvt2((aq.x + bq[h * 32 + d0 + 0]) * QK_SCALE,
                              (aq.y + bq[h * 32 + d0 + 1]) * QK_SCALE));
      st4(qrow + d0 + 2, cvt2((aq.z + bq[h * 32 + d0 + 2]) * QK_SCALE,
                              (aq.w + bq[h * 32 + d0 + 3]) * QK_SCALE));
      st4(krow + d0,     cvt2(ak.x + bk[h * 32 + d0 + 0],
                              ak.y + bk[h * 32 + d0 + 1]));
      st4(krow + d0 + 2, cvt2(ak.z + bk[h * 32 + d0 + 2],
                              ak.w + bk[h * 32 + d0 + 3]));
#pragma unroll
      for (int rr = 0; rr < 4; ++rr) {
        const int d = d0 + rr;
        vo[(bh * 32 + d) * 1024 + nperm] = f2bf(av[rr] + bv[h * 32 + d]);
      }
    }
  }
}

// ---------------------------------------------------------------------------
// K2: flash attention, 128-key chunks, exp2-softmax, packed P stores.
// Grid (16 qtiles, 64 bh); 4 waves x 16 queries. Per iter per wave:
// 8 QK MFMAs + softmax + 8 PV MFMAs, 2 barriers (16+1 total).
// Key axis is stored permuted (c = (k%16)*8 + k/16 within each 128-chunk):
// QK col l15 + nt2-tile -> plds col l15*8+nt2, so each lane's 8 P values
// are contiguous -> pack8 + one ds_write_b128. vo matches (written by K1).
// plds write->read is intra-wave => no barrier between softmax and PV.
// ---------------------------------------------------------------------------
__global__ __launch_bounds__(256) void r18_attn(
    const u16* __restrict__ qw, const u16* __restrict__ kw,
    const u16* __restrict__ vw, float* __restrict__ out)
{
  __shared__ __align__(16) char smem[36352];
  u16 (*klds)[40]  = (u16(*)[40])smem;             // [128][40]  10240B
  u16 (*vlds)[136] = (u16(*)[136])(smem + 10240);  // [32][136]   8704B
  u16 (*plds)[136] = (u16(*)[136])(smem + 18944);  // [64][136]  17408B
  float (*otf)[72] = (float(*)[72])smem;           // aliases klds post-loop

  const int t = threadIdx.x;
  const int qtile = blockIdx.x;
  const int bh = blockIdx.y;
  const int w = t >> 6, lane = t & 63, l15 = lane & 15, quad = lane >> 4;

  // A-frag: A[m=l15][k=quad*8+j] from qw[bh][n][d]
  const s16x8 qfrag = frag16(
      qw + ((size_t)bh * 1024 + qtile * 64 + w * 16 + l15) * 32 + quad * 8);

  f32x4 o0 = {0.f, 0.f, 0.f, 0.f}, o1 = {0.f, 0.f, 0.f, 0.f};
  float mrun[4], lrun[4];
#pragma unroll
  for (int r = 0; r < 4; ++r) { mrun[r] = -1e30f; lrun[r] = 0.f; }

  for (int kb = 0; kb < 8; ++kb) {
    {  // stage K[128][32] and V[32][128] (16 bf16 per thread each)
      const u16* ks_ = kw + ((size_t)bh * 1024 + kb * 128 + (t >> 1)) * 32 + (t & 1) * 16;
      st16(&klds[t >> 1][(t & 1) * 16], ld16(ks_));
      st16(&klds[t >> 1][(t & 1) * 16 + 8], ld16(ks_ + 8));
      const u16* vs_ = vw + ((size_t)bh * 32 + (t >> 3)) * 1024 + kb * 128 + (t & 7) * 16;
      st16(&vlds[t >> 3][(t & 7) * 16], ld16(vs_));
      st16(&vlds[t >> 3][(t & 7) * 16 + 8], ld16(vs_ + 8));
    }
    __syncthreads();

    // QK: 8 n-tiles of 16 keys
    f32x4 s[8];
    const f32x4 zz = {0.f, 0.f, 0.f, 0.f};
#pragma unroll
    for (int nt2 = 0; nt2 < 8; ++nt2) {
      const s16x8 kf = frag16(&klds[nt2 * 16 + l15][quad * 8]);
      s[nt2] = __builtin_amdgcn_mfma_f32_16x16x32_bf16(qfrag, kf, zz, 0, 0, 0);
    }

    // online softmax per C-row (row = quad*4+r), exp2 domain, 128 keys
#pragma unroll
    for (int r = 0; r < 4; ++r) {
      float mx = fmaxf(fmaxf(fmaxf(s[0][r], s[1][r]), fmaxf(s[2][r], s[3][r])),
                       fmaxf(fmaxf(s[4][r], s[5][r]), fmaxf(s[6][r], s[7][r])));
      mx = fmaxf(mx, __shfl_xor(mx, 1));
      mx = fmaxf(mx, __shfl_xor(mx, 2));
      mx = fmaxf(mx, __shfl_xor(mx, 4));
      mx = fmaxf(mx, __shfl_xor(mx, 8));
      const float mnew = fmaxf(mrun[r], mx);
      const float alpha = exp2f(mrun[r] - mnew);
      f32x4 plo, phi;
#pragma unroll
      for (int j = 0; j < 4; ++j) {
        plo[j] = exp2f(s[j][r] - mnew);
        phi[j] = exp2f(s[4 + j][r] - mnew);
      }
      float rs = ((plo.x + plo.y) + (plo.z + plo.w)) +
                 ((phi.x + phi.y) + (phi.z + phi.w));
      rs += __shfl_xor(rs, 1);
      rs += __shfl_xor(rs, 2);
      rs += __shfl_xor(rs, 4);
      rs += __shfl_xor(rs, 8);
      lrun[r] = lrun[r] * alpha + rs;
      mrun[r] = mnew;
      o0[r] *= alpha;
      o1[r] *= alpha;
      // lane's 8 keys -> storage cols l15*8..l15*8+7 (contiguous, permuted)
      st16s(&plds[w * 16 + quad * 4 + r][l15 * 8], pack8(plo, phi));
    }
    // no barrier: plds rows [w*16, w*16+16) written and read by wave w only

    // PV: K=128 in 4 steps of 32 (over permuted key-storage index)
#pragma unroll
    for (int ks = 0; ks < 4; ++ks) {
      const s16x8 pf  = frag16(&plds[w * 16 + l15][ks * 32 + quad * 8]);
      const s16x8 vf0 = frag16(&vlds[l15][ks * 32 + quad * 8]);
      const s16x8 vf1 = frag16(&vlds[16 + l15][ks * 32 + quad * 8]);
      o0 = __builtin_amdgcn_mfma_f32_16x16x32_bf16(pf, vf0, o0, 0, 0, 0);
      o1 = __builtin_amdgcn_mfma_f32_16x16x32_bf16(pf, vf1, o1, 0, 0, 0);
    }
    __syncthreads();   // protect klds/vlds before next staging
  }

  // epilogue: normalize, transpose via otf (aliases klds; loop-end barrier
  // guarantees all frag reads done), coalesced fp32 stores.
#pragma unroll
  for (int r = 0; r < 4; ++r) {
    const float inv = 1.0f / lrun[r];
    otf[l15][w * 16 + quad * 4 + r]      = o0[r] * inv;
    otf[16 + l15][w * 16 + quad * 4 + r] = o1[r] * inv;
  }
  __syncthreads();
  {
    const int dd = t >> 3, i = t & 7;
    const int b = bh >> 3, hh = bh & 7;
    float* dst = out + ((size_t)b * 256 + hh * 32 + dd) * 1024 + qtile * 64 + i * 8;
    f32x4 v0, v1;
#pragma unroll
    for (int jj = 0; jj < 4; ++jj) { v0[jj] = otf[dd][i * 8 + jj];
                                     v1[jj] = otf[dd][i * 8 + 4 + jj]; }
    stf4(dst, v0); stf4(dst + 4, v1);
  }
}

// ---------------------------------------------------------------------------
// K3: out-projection via MFMA, in-place on fp32 d_out. Grid (32 nt, 8 b).
// Block owns the (b, 32-n) slab: stage slab^T [n][c] bf16 (one barrier),
// then a barrier-free K-loop: A-frags from global Wo (fp32->bf16 via
// cvt_pk, 4 insts), B-frags from LDS. Wave w: oc = 64w..64w+63 x 2 ntiles.
// ---------------------------------------------------------------------------
__global__ __launch_bounds__(256) void r18_oproj(
    const float* __restrict__ Wo, const float* __restrict__ bo,
    float* __restrict__ out)
{
  __shared__ u16 o2t[32][264];   // [n_local][c], row stride 528B
  const int t = threadIdx.x;
  const int nt = blockIdx.x, b = blockIdx.y;
  const int w = t >> 6, lane = t & 63, l15 = lane & 15, quad = lane >> 4;

  {  // stage slab: thread t = channel c, 32 n (fp32 -> bf16, transposed)
    const float* src = out + ((size_t)b * 256 + t) * 1024 + nt * 32;
#pragma unroll
    for (int i = 0; i < 32; i += 4) {
      const f32x4 a = ldf4(src + i);
      o2t[i + 0][t] = f2bf(a.x); o2t[i + 1][t] = f2bf(a.y);
      o2t[i + 2][t] = f2bf(a.z); o2t[i + 3][t] = f2bf(a.w);
    }
  }
  __syncthreads();

  f32x4 acc[4][2];
#pragma unroll
  for (int mt = 0; mt < 4; ++mt) {
    acc[mt][0] = (f32x4){0.f, 0.f, 0.f, 0.f};
    acc[mt][1] = (f32x4){0.f, 0.f, 0.f, 0.f};
  }

  for (int ks = 0; ks < 8; ++ks) {
    const s16x8 b0 = frag16(&o2t[l15][ks * 32 + quad * 8]);
    const s16x8 b1 = frag16(&o2t[16 + l15][ks * 32 + quad * 8]);
#pragma unroll
    for (int mt = 0; mt < 4; ++mt) {
      const float* wsrc = Wo + (size_t)(w * 64 + mt * 16 + l15) * 256 + ks * 32 + quad * 8;
      const s16x8 af = pack8(ldf4(wsrc), ldf4(wsrc + 4));
      acc[mt][0] = __builtin_amdgcn_mfma_f32_16x16x32_bf16(af, b0, acc[mt][0], 0, 0, 0);
      acc[mt][1] = __builtin_amdgcn_mfma_f32_16x16x32_bf16(af, b1, acc[mt][1], 0, 0, 0);
    }
  }

  // epilogue: C/D row = quad*4+r (oc), col = l15 (n); coalesced per store
#pragma unroll
  for (int mt = 0; mt < 4; ++mt) {
#pragma unroll
    for (int r = 0; r < 4; ++r) {
      const int oc = w * 64 + mt * 16 + quad * 4 + r;
      const float bov = bo[oc];
      out[((size_t)b * 256 + oc) * 1024 + nt * 32 + l15]      = acc[mt][0][r] + bov;
      out[((size_t)b * 256 + oc) * 1024 + nt * 32 + 16 + l15] = acc[mt][1][r] + bov;
    }
  }
}

// ---------------------------------------------------------------------------
extern "C" void kernel_launch(void* const* d_in, const int* in_sizes, int n_in,
                              void* d_out, int out_size, void* d_ws, size_t ws_size,
                              hipStream_t stream) {
  (void)in_sizes; (void)n_in; (void)out_size; (void)ws_size;
  const float* x  = (const float*)d_in[0];
  const float* Wq = (const float*)d_in[1];
  const float* bq = (const float*)d_in[2];
  const float* Wk = (const float*)d_in[3];
  const float* bk = (const float*)d_in[4];
  const float* Wv = (const float*)d_in[5];
  const float* bv = (const float*)d_in[6];
  const float* Wo = (const float*)d_in[7];
  const float* bo = (const float*)d_in[8];
  float* out = (float*)d_out;

  char* ws = (char*)d_ws;                    // 12 MB
  u16* qw = (u16*)(ws);                      // [bh][n][d] bf16, 4MB
  u16* kw = (u16*)(ws + (4u << 20));         // [bh][n][d] bf16, 4MB
  u16* vw = (u16*)(ws + (8u << 20));         // [bh][d][nperm] bf16, 4MB

  r18_qkv<<<dim3(16, 4, 8), 256, 0, stream>>>(
      x, Wq, bq, Wk, bk, Wv, bv, qw, kw, vw);
  r18_attn<<<dim3(16, 64), 256, 0, stream>>>(qw, kw, vw, out);
  r18_oproj<<<dim3(32, 8), 256, 0, stream>>>(Wo, bo, out);
}

// Round 2
// 137.470 us; speedup vs baseline: 1.1059x; 1.0983x over previous
//
#include <hip/hip_runtime.h>
#include <math.h>

// Problem: B=8, C=256, N=H*W=1024, nh=8, dk=dv=32. fp32 in/out, bf16 ws.
// Round 19: swapped QK^T -> lane-local softmax, zero-LDS P.
//   K1 qkv : as r18, but V written with the PV-matched key permutation
//            c(k) = (nt>>1)*32 + quad*8 + (nt&1)*4 + r.
//   K2 attn: mfma(K,Q) gives S^T (lane = 1 query x 32 keys). Softmax is
//            in-lane + 2 cross-quad shuffles. PV: O^T = V^T * P^T with
//            B-frag packed from the lane's own registers (no plds at all).
//            K/V reg-prefetch one chunk ahead (T14). LDS 36.4->18.9 KB.
//   K3 oproj: unchanged.
typedef unsigned short u16;
typedef __attribute__((ext_vector_type(8))) unsigned short u16x8;
typedef __attribute__((ext_vector_type(8))) short s16x8;   // MFMA A/B frag
typedef __attribute__((ext_vector_type(4))) float f32x4;   // MFMA C/D

// logits scale 1/sqrt(32) folded with log2(e) so softmax uses exp2 directly
#define QK_SCALE (0.17677669529663687f * 1.4426950408889634f)

__device__ __forceinline__ unsigned cvt2(float lo, float hi) {
  unsigned r;  // D[15:0]=bf16_rne(lo), D[31:16]=bf16_rne(hi)
  asm("v_cvt_pk_bf16_f32 %0, %1, %2" : "=v"(r) : "v"(lo), "v"(hi));
  return r;
}
__device__ __forceinline__ u16 f2bf(float f) { return (u16)cvt2(f, f); }
__device__ __forceinline__ u16x8 ld16(const void* p) { u16x8 v; __builtin_memcpy(&v, p, 16); return v; }
__device__ __forceinline__ void st16(void* p, u16x8 v) { __builtin_memcpy(p, &v, 16); }
__device__ __forceinline__ void st16s(void* p, s16x8 v) { __builtin_memcpy(p, &v, 16); }
__device__ __forceinline__ void st4(void* p, unsigned v) { __builtin_memcpy(p, &v, 4); }
__device__ __forceinline__ f32x4 ldf4(const void* p) { f32x4 v; __builtin_memcpy(&v, p, 16); return v; }
__device__ __forceinline__ void stf4(void* p, f32x4 v) { __builtin_memcpy(p, &v, 16); }
__device__ __forceinline__ s16x8 frag16(const void* p) { s16x8 v; __builtin_memcpy(&v, p, 16); return v; }
__device__ __forceinline__ s16x8 pack8(f32x4 lo, f32x4 hi) {
  union { unsigned u[4]; s16x8 s; } c;
  c.u[0] = cvt2(lo.x, lo.y); c.u[1] = cvt2(lo.z, lo.w);
  c.u[2] = cvt2(hi.x, hi.y); c.u[3] = cvt2(hi.z, hi.w);
  return c.s;
}

// ---------------------------------------------------------------------------
// K1: QKV projection via MFMA. Grid (16 nt, 4 head-pairs, 8 b), 256 thr.
// Block: heads {2hp, 2hp+1}, 64-n tile. Wave w = ntile w (16 n). K=256, 8x32.
// LDS: xt[64][264] bf16 (x^T tile, [n][c]) 33.8KB + wlds[192][40] 15KB.
// wlds rows: [0,64)=Wq(h0,h1) [64,128)=Wk [128,192)=Wv.
// Epilogue: q,k -> [bh][n][d] (q pre-scaled, dword-pair stores);
//           v -> [bh][d][nperm], key-permuted within each 128-chunk so that
//           K2's PV B-frag slot (ks,quad,hi,r) maps to the lane's own
//           QK output: c = ((nt>>1)<<5)|(q4<<3)|((nt&1)<<2)|r,
//           where nt=sig>>4, q4=(sig>>2)&3, r=sig&3, sig=n&127.
// ---------------------------------------------------------------------------
__global__ __launch_bounds__(256) void r19_qkv(
    const float* __restrict__ x,
    const float* __restrict__ Wq, const float* __restrict__ bq,
    const float* __restrict__ Wk, const float* __restrict__ bk,
    const float* __restrict__ Wv, const float* __restrict__ bv,
    u16* __restrict__ qo, u16* __restrict__ ko, u16* __restrict__ vo)
{
  __shared__ u16 xt[64][264];    // [n_local][c], row stride 528B
  __shared__ u16 wlds[192][40];

  const int t = threadIdx.x;
  const int ntile = blockIdx.x, hp = blockIdx.y, b = blockIdx.z;
  const int n0 = ntile * 64, h0 = hp * 2;
  const int w = t >> 6, lane = t & 63, l15 = lane & 15, quad = lane >> 4;

  {  // stage x^T: thread t = channel c, 64 n (fp32 -> bf16, transposed)
    const float* xrow = x + ((size_t)b * 256 + t) * 1024 + n0;
#pragma unroll
    for (int i = 0; i < 64; i += 4) {
      const f32x4 a = ldf4(xrow + i);
      xt[i + 0][t] = f2bf(a.x); xt[i + 1][t] = f2bf(a.y);
      xt[i + 2][t] = f2bf(a.z); xt[i + 3][t] = f2bf(a.w);
    }
  }

  f32x4 acc[12];
#pragma unroll
  for (int i = 0; i < 12; ++i) acc[i] = (f32x4){0.f, 0.f, 0.f, 0.f};

  for (int ks = 0; ks < 8; ++ks) {
    __syncthreads();   // protect wlds reuse (and xt staging on ks=0)
    if (t < 192) {     // stage W chunk: thread t = one 32-c row
      const int m = t >> 6, hh = (t >> 5) & 1, r = t & 31;
      const float* M = (m == 0) ? Wq : (m == 1) ? Wk : Wv;
      const float* src = M + (size_t)((h0 + hh) * 32 + r) * 256 + ks * 32;
      st16s(&wlds[t][0],  pack8(ldf4(src),      ldf4(src + 4)));
      st16s(&wlds[t][8],  pack8(ldf4(src + 8),  ldf4(src + 12)));
      st16s(&wlds[t][16], pack8(ldf4(src + 16), ldf4(src + 20)));
      st16s(&wlds[t][24], pack8(ldf4(src + 24), ldf4(src + 28)));
    }
    __syncthreads();

    const s16x8 bfrag = frag16(&xt[w * 16 + l15][ks * 32 + quad * 8]);
#pragma unroll
    for (int mt = 0; mt < 12; ++mt) {
      const s16x8 af = frag16(&wlds[mt * 16 + l15][quad * 8]);
      acc[mt] = __builtin_amdgcn_mfma_f32_16x16x32_bf16(af, bfrag, acc[mt], 0, 0, 0);
    }
  }

  // epilogue: C/D row = quad*4+rr (d within 16), col = l15 (n within 16)
  const int n = n0 + w * 16 + l15;
  const int sig = n & 127;
  const int ntn = sig >> 4, q4 = (sig >> 2) & 3, rn = sig & 3;
  const int nperm = (n & ~127) | ((ntn >> 1) << 5) | (q4 << 3) | ((ntn & 1) << 2) | rn;
#pragma unroll
  for (int hh = 0; hh < 2; ++hh) {
    const int h = h0 + hh;
    const size_t bh = (size_t)(b * 8 + h);
    u16* qrow = qo + (bh * 1024 + n) * 32;
    u16* krow = ko + (bh * 1024 + n) * 32;
#pragma unroll
    for (int half = 0; half < 2; ++half) {
      const int d0 = half * 16 + quad * 4;
      const f32x4 aq = acc[hh * 2 + half];
      const f32x4 ak = acc[4 + hh * 2 + half];
      const f32x4 av = acc[8 + hh * 2 + half];
      st4(qrow + d0,     cvt2((aq.x + bq[h * 32 + d0 + 0]) * QK_SCALE,
                              (aq.y + bq[h * 32 + d0 + 1]) * QK_SCALE));
      st4(qrow + d0 + 2, cvt2((aq.z + bq[h * 32 + d0 + 2]) * QK_SCALE,
                              (aq.w + bq[h * 32 + d0 + 3]) * QK_SCALE));
      st4(krow + d0,     cvt2(ak.x + bk[h * 32 + d0 + 0],
                              ak.y + bk[h * 32 + d0 + 1]));
      st4(krow + d0 + 2, cvt2(ak.z + bk[h * 32 + d0 + 2],
                              ak.w + bk[h * 32 + d0 + 3]));
#pragma unroll
      for (int rr = 0; rr < 4; ++rr) {
        const int d = d0 + rr;
        vo[(bh * 32 + d) * 1024 + nperm] = f2bf(av[rr] + bv[h * 32 + d]);
      }
    }
  }
}

// ---------------------------------------------------------------------------
// K2: flash attention, swapped QK^T, zero-LDS P. Grid (16 qtiles, 64 bh);
// 4 waves x 16 queries. QK: mfma(K,Q) -> lane holds S^T[32 keys][1 query]:
// key = nt2*16 + quad*4 + r, query = w*16 + l15. Softmax: in-lane reduce
// (31 ops) + shfl_xor(16/32) across quads; mrun/lrun are scalars.
// PV: O^T = V^T * P^T; A-frag = vlds (d rows), B-frag = pack8 of the lane's
// own p regs -- valid because V's key axis is stored permuted by K1 so that
// storage ks*32+quad*8+hi*4+r == natural key 16*(2ks+hi)+quad*4+r.
// K/V staged via reg-prefetch one chunk ahead (T14); 2 barriers/iter.
// LDS 18.9 KB (plds/otf gone). Epilogue: direct coalesced 4B stores
// (C rows are d-channels now -- matches out[b][c][n]).
// ---------------------------------------------------------------------------
__global__ __launch_bounds__(256) void r19_attn(
    const u16* __restrict__ qw, const u16* __restrict__ kw,
    const u16* __restrict__ vw, float* __restrict__ out)
{
  __shared__ u16 klds[128][40];   // [key][d]   10240B
  __shared__ u16 vlds[32][136];   // [d][kperm]  8704B

  const int t = threadIdx.x;
  const int qtile = blockIdx.x;
  const int bh = blockIdx.y;
  const int w = t >> 6, lane = t & 63, l15 = lane & 15, quad = lane >> 4;

  // B-frag: B[k=quad*8+j][n=l15] = Q[query w*16+l15][d=quad*8+j]
  const s16x8 qfrag = frag16(
      qw + ((size_t)bh * 1024 + qtile * 64 + w * 16 + l15) * 32 + quad * 8);

  // staging addresses: K row t>>1 (2 thr/row), V row t>>3 (8 thr/row)
  const u16* kbase = kw + ((size_t)bh * 1024 + (t >> 1)) * 32 + (t & 1) * 16;
  const u16* vbase = vw + ((size_t)bh * 32 + (t >> 3)) * 1024 + (t & 7) * 16;

  u16x8 gk0 = ld16(kbase), gk1 = ld16(kbase + 8);
  u16x8 gv0 = ld16(vbase), gv1 = ld16(vbase + 8);

  f32x4 o0 = {0.f, 0.f, 0.f, 0.f}, o1 = {0.f, 0.f, 0.f, 0.f};
  float mrun = -1e30f, lrun = 0.f;

  for (int kb = 0; kb < 8; ++kb) {
    if (kb) __syncthreads();       // all waves done reading previous chunk
    st16(&klds[t >> 1][(t & 1) * 16], gk0);
    st16(&klds[t >> 1][(t & 1) * 16 + 8], gk1);
    st16(&vlds[t >> 3][(t & 7) * 16], gv0);
    st16(&vlds[t >> 3][(t & 7) * 16 + 8], gv1);
    if (kb < 7) {                  // prefetch next chunk into regs (T14)
      const u16* kn = kbase + (size_t)(kb + 1) * (128 * 32);
      const u16* vn = vbase + (size_t)(kb + 1) * 128;
      gk0 = ld16(kn); gk1 = ld16(kn + 8);
      gv0 = ld16(vn); gv1 = ld16(vn + 8);
    }
    __syncthreads();               // staging visible

    // QK^T swapped: s[nt2][r] = S[key nt2*16+quad*4+r][query w*16+l15]
    f32x4 s[8];
    const f32x4 zz = {0.f, 0.f, 0.f, 0.f};
#pragma unroll
    for (int nt2 = 0; nt2 < 8; ++nt2) {
      const s16x8 kf = frag16(&klds[nt2 * 16 + l15][quad * 8]);
      s[nt2] = __builtin_amdgcn_mfma_f32_16x16x32_bf16(kf, qfrag, zz, 0, 0, 0);
    }

    // online softmax: in-lane over 32 keys + cross-quad reduce (xor 16,32)
    float mx = fmaxf(fmaxf(s[0][0], s[0][1]), fmaxf(s[0][2], s[0][3]));
#pragma unroll
    for (int nt2 = 1; nt2 < 8; ++nt2)
      mx = fmaxf(mx, fmaxf(fmaxf(s[nt2][0], s[nt2][1]),
                           fmaxf(s[nt2][2], s[nt2][3])));
    mx = fmaxf(mx, __shfl_xor(mx, 16));
    mx = fmaxf(mx, __shfl_xor(mx, 32));
    const float mnew = fmaxf(mrun, mx);
    const float alpha = exp2f(mrun - mnew);
    float rs = 0.f;
#pragma unroll
    for (int nt2 = 0; nt2 < 8; ++nt2) {
#pragma unroll
      for (int r = 0; r < 4; ++r) {
        s[nt2][r] = exp2f(s[nt2][r] - mnew);
        rs += s[nt2][r];
      }
    }
    rs += __shfl_xor(rs, 16);
    rs += __shfl_xor(rs, 32);
    lrun = lrun * alpha + rs;
    mrun = mnew;
#pragma unroll
    for (int r = 0; r < 4; ++r) { o0[r] *= alpha; o1[r] *= alpha; }

    // PV: O^T = V^T * P^T; B-frag slot (quad, j=hi*4+r) = p[2ks+hi][r]
#pragma unroll
    for (int ks = 0; ks < 4; ++ks) {
      const s16x8 pf  = pack8(s[2 * ks], s[2 * ks + 1]);
      const s16x8 vf0 = frag16(&vlds[l15][ks * 32 + quad * 8]);
      const s16x8 vf1 = frag16(&vlds[16 + l15][ks * 32 + quad * 8]);
      o0 = __builtin_amdgcn_mfma_f32_16x16x32_bf16(vf0, pf, o0, 0, 0, 0);
      o1 = __builtin_amdgcn_mfma_f32_16x16x32_bf16(vf1, pf, o1, 0, 0, 0);
    }
  }

  // epilogue: lane holds O^T[d][query l15]; rows are channels -> direct
  // coalesced stores (16 lanes x 4B contiguous per quad-row).
  const float inv = 1.0f / lrun;
  const int b = bh >> 3, hh = bh & 7;
  float* obase = out + ((size_t)b * 256 + hh * 32) * 1024
               + qtile * 64 + w * 16 + l15;
#pragma unroll
  for (int r = 0; r < 4; ++r) {
    obase[(size_t)(quad * 4 + r) * 1024]      = o0[r] * inv;
    obase[(size_t)(16 + quad * 4 + r) * 1024] = o1[r] * inv;
  }
}

// ---------------------------------------------------------------------------
// K3: out-projection via MFMA, in-place on fp32 d_out. Grid (32 nt, 8 b).
// Block owns the (b, 32-n) slab: stage slab^T [n][c] bf16 (one barrier),
// then a barrier-free K-loop: A-frags from global Wo (fp32->bf16 via
// cvt_pk, 4 insts), B-frags from LDS. Wave w: oc = 64w..64w+63 x 2 ntiles.
// ---------------------------------------------------------------------------
__global__ __launch_bounds__(256) void r19_oproj(
    const float* __restrict__ Wo, const float* __restrict__ bo,
    float* __restrict__ out)
{
  __shared__ u16 o2t[32][264];   // [n_local][c], row stride 528B
  const int t = threadIdx.x;
  const int nt = blockIdx.x, b = blockIdx.y;
  const int w = t >> 6, lane = t & 63, l15 = lane & 15, quad = lane >> 4;

  {  // stage slab: thread t = channel c, 32 n (fp32 -> bf16, transposed)
    const float* src = out + ((size_t)b * 256 + t) * 1024 + nt * 32;
#pragma unroll
    for (int i = 0; i < 32; i += 4) {
      const f32x4 a = ldf4(src + i);
      o2t[i + 0][t] = f2bf(a.x); o2t[i + 1][t] = f2bf(a.y);
      o2t[i + 2][t] = f2bf(a.z); o2t[i + 3][t] = f2bf(a.w);
    }
  }
  __syncthreads();

  f32x4 acc[4][2];
#pragma unroll
  for (int mt = 0; mt < 4; ++mt) {
    acc[mt][0] = (f32x4){0.f, 0.f, 0.f, 0.f};
    acc[mt][1] = (f32x4){0.f, 0.f, 0.f, 0.f};
  }

  for (int ks = 0; ks < 8; ++ks) {
    const s16x8 b0 = frag16(&o2t[l15][ks * 32 + quad * 8]);
    const s16x8 b1 = frag16(&o2t[16 + l15][ks * 32 + quad * 8]);
#pragma unroll
    for (int mt = 0; mt < 4; ++mt) {
      const float* wsrc = Wo + (size_t)(w * 64 + mt * 16 + l15) * 256 + ks * 32 + quad * 8;
      const s16x8 af = pack8(ldf4(wsrc), ldf4(wsrc + 4));
      acc[mt][0] = __builtin_amdgcn_mfma_f32_16x16x32_bf16(af, b0, acc[mt][0], 0, 0, 0);
      acc[mt][1] = __builtin_amdgcn_mfma_f32_16x16x32_bf16(af, b1, acc[mt][1], 0, 0, 0);
    }
  }

  // epilogue: C/D row = quad*4+r (oc), col = l15 (n); coalesced per store
#pragma unroll
  for (int mt = 0; mt < 4; ++mt) {
#pragma unroll
    for (int r = 0; r < 4; ++r) {
      const int oc = w * 64 + mt * 16 + quad * 4 + r;
      const float bov = bo[oc];
      out[((size_t)b * 256 + oc) * 1024 + nt * 32 + l15]      = acc[mt][0][r] + bov;
      out[((size_t)b * 256 + oc) * 1024 + nt * 32 + 16 + l15] = acc[mt][1][r] + bov;
    }
  }
}

// ---------------------------------------------------------------------------
extern "C" void kernel_launch(void* const* d_in, const int* in_sizes, int n_in,
                              void* d_out, int out_size, void* d_ws, size_t ws_size,
                              hipStream_t stream) {
  (void)in_sizes; (void)n_in; (void)out_size; (void)ws_size;
  const float* x  = (const float*)d_in[0];
  const float* Wq = (const float*)d_in[1];
  const float* bq = (const float*)d_in[2];
  const float* Wk = (const float*)d_in[3];
  const float* bk = (const float*)d_in[4];
  const float* Wv = (const float*)d_in[5];
  const float* bv = (const float*)d_in[6];
  const float* Wo = (const float*)d_in[7];
  const float* bo = (const float*)d_in[8];
  float* out = (float*)d_out;

  char* ws = (char*)d_ws;                    // 12 MB
  u16* qw = (u16*)(ws);                      // [bh][n][d] bf16, 4MB
  u16* kw = (u16*)(ws + (4u << 20));         // [bh][n][d] bf16, 4MB
  u16* vw = (u16*)(ws + (8u << 20));         // [bh][d][nperm] bf16, 4MB

  r19_qkv<<<dim3(16, 4, 8), 256, 0, stream>>>(
      x, Wq, bq, Wk, bk, Wv, bv, qw, kw, vw);
  r19_attn<<<dim3(16, 64), 256, 0, stream>>>(qw, kw, vw, out);
  r19_oproj<<<dim3(32, 8), 256, 0, stream>>>(Wo, bo, out);
}